// Round 4
// baseline (1100.005 us; speedup 1.0000x reference)
//
#include <hip/hip_runtime.h>
#include <hip/hip_bf16.h>

#define DEV __device__ __forceinline__

static constexpr int Bn = 16;
static constexpr int Cc = 4;
static constexpr int HW = 4096;      // L (=64*64)
static constexpr int BL = Bn * HW;   // 65536 rows
static constexpr int DM = 64;
static constexpr int DI = 128;
static constexpr int NS = 16;        // D_STATE
static constexpr int NC = 64;        // chunks per sequence
static constexpr int CS = HW / NC;   // 64 steps per chunk

DEV float softplus_f(float x) { return fmaxf(x, 0.f) + log1pf(__expf(-fabsf(x))); }
DEV float sigmoid_f(float x) { return 1.f / (1.f + __expf(-x)); }

// ---------------- embed: feat[b,l,m] = sum_c z[b,c,l]*ew[m,c] + eb[m] ----------
__global__ __launch_bounds__(256) void k_embed(const float* __restrict__ z,
                                               const float* __restrict__ ew,
                                               const float* __restrict__ eb,
                                               float* __restrict__ feat) {
    int idx = blockIdx.x * 256 + threadIdx.x;          // over BL*DM
    if (idx >= BL * DM) return;
    int m = idx & 63;
    int bl = idx >> 6;
    int b = bl >> 12;
    int hw = bl & 4095;
    const float* zp = z + (size_t)b * Cc * HW + hw;
    float acc = eb[m];
#pragma unroll
    for (int c = 0; c < 4; ++c) acc += zp[(size_t)c * HW] * ew[m * 4 + c];
    feat[idx] = acc;
}

// ------------- generic linear: out[r, n0+j] = sum_k in[r,k] * W[n0+j, k] -------
// W is [Nfull, K] row-major (f32). Block: 256 threads, RC rows x NT cols at once.
template <int K, int NT, int RC>
__global__ __launch_bounds__(256) void k_linear(const float* __restrict__ in,
                                                const float* __restrict__ W,
                                                float* __restrict__ out,
                                                int R, int Nfull) {
    __shared__ float Wt[K * NT];       // transposed: Wt[k*NT + j]
    __shared__ float irow[RC * K];
    int tid = threadIdx.x;
    int n0 = blockIdx.y * NT;
    for (int i = tid; i < K * NT; i += 256) {
        int k = i / NT;
        int j = i - k * NT;
        Wt[i] = W[(size_t)(n0 + j) * K + k];
    }
    __syncthreads();
    int ngroups = (R + RC - 1) / RC;
    for (int g = blockIdx.x; g < ngroups; g += gridDim.x) {
        int row0 = g * RC;
        int nr = (R - row0 < RC) ? (R - row0) : RC;
        for (int i = tid; i < nr * K; i += 256) irow[i] = in[(size_t)row0 * K + i];
        __syncthreads();
        int r = tid / NT;
        int j = tid - r * NT;
        if (r < nr) {
            float acc = 0.f;
#pragma unroll
            for (int k = 0; k < K; ++k) acc += irow[r * K + k] * Wt[k * NT + j];
            out[(size_t)(row0 + r) * Nfull + n0 + j] = acc;
        }
        __syncthreads();
    }
}

// ----------- causal depthwise conv (K=4) + SiLU: u[b,t,d] -----------------------
__global__ __launch_bounds__(256) void k_conv(const float* __restrict__ xz,
                                              const float* __restrict__ cw,
                                              const float* __restrict__ cb,
                                              float* __restrict__ u) {
    int idx = blockIdx.x * 256 + threadIdx.x;          // over BL*DI
    if (idx >= BL * DI) return;
    int d = idx & 127;
    int bl = idx >> 7;
    int b = bl >> 12;
    int t = bl & 4095;
    float acc = cb[d];
    const float* xp = xz + ((size_t)b * HW) * 256 + d; // u-half column d
#pragma unroll
    for (int k = 0; k < 4; ++k) {
        int tt = t - 3 + k;
        if (tt >= 0) acc += cw[d * 4 + k] * xp[(size_t)tt * 256];
    }
    u[idx] = acc * sigmoid_f(acc);
}

// ---------------- scan pass 1: per-chunk local scan (h0 = 0) -------------------
__global__ __launch_bounds__(128) void k_scan1(const float* __restrict__ u,
                                               const float* __restrict__ xdbl,
                                               const float* __restrict__ dpw,
                                               const float* __restrict__ dpb,
                                               const float* __restrict__ Alog,
                                               float* __restrict__ cS,
                                               float* __restrict__ cDT) {
    int blk = blockIdx.x;   // b*NC + c
    int b = blk >> 6;
    int c = blk & (NC - 1);
    int d = threadIdx.x;
    float a[NS];
#pragma unroll
    for (int n = 0; n < NS; ++n) a[n] = -__expf(Alog[d * NS + n]);
    float w0 = dpw[d * 4 + 0], w1 = dpw[d * 4 + 1],
          w2 = dpw[d * 4 + 2], w3 = dpw[d * 4 + 3];
    float bb = dpb[d];
    float h[NS];
#pragma unroll
    for (int n = 0; n < NS; ++n) h[n] = 0.f;
    float sdt = 0.f;
    int t0 = c * CS;
    for (int tt = 0; tt < CS; ++tt) {
        size_t base = (size_t)b * HW + t0 + tt;
        const float* xd = xdbl + base * 36;
        float dt = softplus_f(w0 * xd[0] + w1 * xd[1] + w2 * xd[2] + w3 * xd[3] + bb);
        float uu = u[base * DI + d];
        float du = dt * uu;
        sdt += dt;
#pragma unroll
        for (int n = 0; n < NS; ++n) {
            float dA = __expf(dt * a[n]);
            h[n] = dA * h[n] + du * xd[4 + n];
        }
    }
    size_t o = (size_t)blk * DI + d;
    cDT[o] = sdt;
#pragma unroll
    for (int n = 0; n < NS; ++n) cS[o * NS + n] = h[n];
}

// ------------- scan pass 2: sequential chunk combine per (b,d,n) ---------------
__global__ __launch_bounds__(256) void k_scan2(const float* __restrict__ cS,
                                               const float* __restrict__ cDT,
                                               const float* __restrict__ Alog,
                                               float* __restrict__ iS) {
    int idx = blockIdx.x * 256 + threadIdx.x;          // over Bn*DI*NS
    if (idx >= Bn * DI * NS) return;
    int n = idx & 15;
    int d = (idx >> 4) & 127;
    int b = idx >> 11;
    float a = -__expf(Alog[d * NS + n]);
    float h = 0.f;
    for (int c = 0; c < NC; ++c) {
        size_t o = (size_t)(b * NC + c) * DI + d;
        iS[o * NS + n] = h;
        h = __expf(a * cDT[o]) * h + cS[o * NS + n];
    }
}

// ------- scan pass 3: re-scan with proper h0, emit gated y (overwrites u) ------
__global__ __launch_bounds__(128) void k_scan3(float* __restrict__ uy,
                                               const float* __restrict__ xz,
                                               const float* __restrict__ xdbl,
                                               const float* __restrict__ dpw,
                                               const float* __restrict__ dpb,
                                               const float* __restrict__ Alog,
                                               const float* __restrict__ Dp,
                                               const float* __restrict__ iS) {
    int blk = blockIdx.x;
    int b = blk >> 6;
    int c = blk & (NC - 1);
    int d = threadIdx.x;
    float a[NS];
#pragma unroll
    for (int n = 0; n < NS; ++n) a[n] = -__expf(Alog[d * NS + n]);
    float w0 = dpw[d * 4 + 0], w1 = dpw[d * 4 + 1],
          w2 = dpw[d * 4 + 2], w3 = dpw[d * 4 + 3];
    float bb = dpb[d];
    float Dv = Dp[d];
    float h[NS];
    size_t so = (size_t)blk * DI + d;
#pragma unroll
    for (int n = 0; n < NS; ++n) h[n] = iS[so * NS + n];
    int t0 = c * CS;
    for (int tt = 0; tt < CS; ++tt) {
        size_t base = (size_t)b * HW + t0 + tt;
        const float* xd = xdbl + base * 36;
        float dt = softplus_f(w0 * xd[0] + w1 * xd[1] + w2 * xd[2] + w3 * xd[3] + bb);
        float uu = uy[base * DI + d];
        float du = dt * uu;
        float y = 0.f;
#pragma unroll
        for (int n = 0; n < NS; ++n) {
            float dA = __expf(dt * a[n]);
            h[n] = dA * h[n] + du * xd[4 + n];
            y += h[n] * xd[20 + n];
        }
        y += uu * Dv;
        float zz = xz[base * 256 + 128 + d];
        y *= zz * sigmoid_f(zz);
        uy[base * DI + d] = y;
    }
}

// ---------------- layernorm over last dim (64), in place -----------------------
__global__ __launch_bounds__(256) void k_ln(float* __restrict__ feat,
                                            const float* __restrict__ g,
                                            const float* __restrict__ bta, int R) {
    int lane = threadIdx.x & 63;
    int wv = blockIdx.x * 4 + (threadIdx.x >> 6);
    int stride = gridDim.x * 4;
    for (int row = wv; row < R; row += stride) {
        float x = feat[(size_t)row * 64 + lane];
        float s = x;
#pragma unroll
        for (int off = 32; off; off >>= 1) s += __shfl_xor(s, off, 64);
        float mu = s * (1.f / 64.f);
        float xm = x - mu;
        float v = xm * xm;
#pragma unroll
        for (int off = 32; off; off >>= 1) v += __shfl_xor(v, off, 64);
        float var = v * (1.f / 64.f);
        feat[(size_t)row * 64 + lane] = xm * rsqrtf(var + 1e-5f) * g[lane] + bta[lane];
    }
}

// ---------------- head + residual: out = z - (feat @ head_w.T + head_b) --------
__global__ __launch_bounds__(256) void k_head(const float* __restrict__ feat,
                                              const float* __restrict__ hwt,
                                              const float* __restrict__ hb,
                                              const float* __restrict__ z,
                                              float* __restrict__ out) {
    __shared__ float fl[64 * 65];
    int row0 = blockIdx.x * 64;
    for (int i = threadIdx.x; i < 64 * 64; i += 256) {
        int r = i >> 6;
        int m = i & 63;
        fl[r * 65 + m] = feat[(size_t)(row0 + r) * 64 + m];
    }
    __syncthreads();
    int r = threadIdx.x >> 2;
    int c = threadIdx.x & 3;
    float acc = hb[c];
#pragma unroll
    for (int m = 0; m < 64; ++m) acc += fl[r * 65 + m] * hwt[c * 64 + m];
    int bl = row0 + r;
    int b = bl >> 12;
    int hw = bl & 4095;
    size_t o = ((size_t)b * 4 + c) * HW + hw;
    out[o] = z[o] - acc;
}

// -------------------------------------------------------------------------------
static void run_mamba(const float* const* P, float* feat, float* xz, float* u,
                      float* xdbl, float* cS, float* cDT, float* iS,
                      hipStream_t s) {
    // P: 0 in_proj_w, 1 conv_w, 2 conv_b, 3 x_proj_w, 4 dt_proj_w, 5 dt_proj_b,
    //    6 A_log, 7 D, 8 out_proj_w
    k_linear<64, 128, 2><<<dim3(2048, 2), 256, 0, s>>>(feat, P[0], xz, BL, 256);
    k_conv<<<(BL * DI) / 256, 256, 0, s>>>(xz, P[1], P[2], u);
    k_linear<128, 36, 7><<<dim3(2048, 1), 256, 0, s>>>(u, P[3], xdbl, BL, 36);
    k_scan1<<<Bn * NC, DI, 0, s>>>(u, xdbl, P[4], P[5], P[6], cS, cDT);
    k_scan2<<<(Bn * DI * NS) / 256, 256, 0, s>>>(cS, cDT, P[6], iS);
    k_scan3<<<Bn * NC, DI, 0, s>>>(u, xz, xdbl, P[4], P[5], P[6], P[7], iS);
    k_linear<128, 64, 4><<<dim3(2048, 1), 256, 0, s>>>(u, P[8], feat, BL, 64);
}

extern "C" void kernel_launch(void* const* d_in, const int* in_sizes, int n_in,
                              void* d_out, int out_size, void* d_ws, size_t ws_size,
                              hipStream_t stream) {
    const float* z = (const float*)d_in[0];
    const float* ew = (const float*)d_in[1];
    const float* eb = (const float*)d_in[2];
    const float* m1[9];
    const float* m2[9];
    for (int i = 0; i < 9; ++i) m1[i] = (const float*)d_in[3 + i];
    for (int i = 0; i < 9; ++i) m2[i] = (const float*)d_in[12 + i];
    const float* ln1g = (const float*)d_in[21];
    const float* ln1b = (const float*)d_in[22];
    const float* ln2g = (const float*)d_in[23];
    const float* ln2b = (const float*)d_in[24];
    const float* hwt = (const float*)d_in[25];
    const float* hb = (const float*)d_in[26];

    float* ws = (float*)d_ws;
    float* feat = ws;                         // BL*64
    float* xz = feat + (size_t)BL * 64;       // BL*256
    float* u = xz + (size_t)BL * 256;         // BL*128
    float* xdbl = u + (size_t)BL * 128;       // BL*36
    float* cS = xdbl + (size_t)BL * 36;       // Bn*NC*DI*NS
    float* cDT = cS + (size_t)Bn * NC * DI * NS;  // Bn*NC*DI
    float* iS = cDT + (size_t)Bn * NC * DI;   // Bn*NC*DI*NS

    k_embed<<<(BL * DM) / 256, 256, 0, stream>>>(z, ew, eb, feat);

    run_mamba(m1, feat, xz, u, xdbl, cS, cDT, iS, stream);
    k_ln<<<4096, 256, 0, stream>>>(feat, ln1g, ln1b, BL);
    run_mamba(m2, feat, xz, u, xdbl, cS, cDT, iS, stream);
    k_ln<<<4096, 256, 0, stream>>>(feat, ln2g, ln2b, BL);

    k_head<<<BL / 64, 256, 0, stream>>>(feat, hwt, hb, z, (float*)d_out);
}

// Round 5
// 765.539 us; speedup vs baseline: 1.4369x; 1.4369x over previous
//
#include <hip/hip_runtime.h>
#include <hip/hip_bf16.h>

#define DEV __device__ __forceinline__

static constexpr int Bn = 16;
static constexpr int Cc = 4;
static constexpr int HW = 4096;      // L (=64*64)
static constexpr int BL = Bn * HW;   // 65536 rows
static constexpr int DM = 64;
static constexpr int DI = 128;
static constexpr int NS = 16;        // D_STATE
static constexpr int NC = 64;        // chunks per sequence
static constexpr int CS = HW / NC;   // 64 steps per chunk

DEV float softplus_f(float x) { return fmaxf(x, 0.f) + log1pf(__expf(-fabsf(x))); }
DEV float sigmoid_f(float x) { return 1.f / (1.f + __expf(-x)); }

// ---------------- embed: feat[b,l,m] = sum_c z[b,c,l]*ew[m,c] + eb[m] ----------
__global__ __launch_bounds__(256) void k_embed(const float* __restrict__ z,
                                               const float* __restrict__ ew,
                                               const float* __restrict__ eb,
                                               float* __restrict__ feat) {
    int idx = blockIdx.x * 256 + threadIdx.x;          // over BL*DM
    if (idx >= BL * DM) return;
    int m = idx & 63;
    int bl = idx >> 6;
    int b = bl >> 12;
    int hw = bl & 4095;
    const float* zp = z + (size_t)b * Cc * HW + hw;
    float acc = eb[m];
#pragma unroll
    for (int c = 0; c < 4; ++c) acc += zp[(size_t)c * HW] * ew[m * 4 + c];
    feat[idx] = acc;
}

// ---- register-tiled GEMM: out[r, n0+c] = sum_k in[r,k] * W[n0+c, k] -----------
// Block tile: 64 rows x BN cols. Thread tile: 4 x TN. 256 threads/block.
// A staged [64][K+4] row-major (float4 k-reads); W staged transposed [K][BN+4].
// LDS bytes/FMA = 2 (vs 8 for the round-3 one-output-per-thread kernel).
template <int K, int BN, int TN>
__global__ __launch_bounds__(256) void k_gemm(const float* __restrict__ in,
                                              const float* __restrict__ W,
                                              float* __restrict__ out,
                                              int Nfull) {
    constexpr int BM = 64, TM = 4;
    constexpr int CT = BN / TN;        // threads along cols
    constexpr int RT = BM / TM;        // 16 threads along rows
    constexpr int KP = K + 4;          // A row stride (16B aligned, conflict-light)
    constexpr int WP = BN + 4;         // Ws row stride
    __shared__ float As[BM * KP];
    __shared__ float Ws[K * WP];
    int tid = threadIdx.x;
    int n0 = blockIdx.y * BN;
    int row0 = blockIdx.x * BM;
    // stage W transposed: Ws[k][c] = W[n0+c][k]
    for (int i = tid; i < BN * (K / 4); i += 256) {
        int c = i / (K / 4);
        int k4 = i - c * (K / 4);
        float4 w = *reinterpret_cast<const float4*>(&W[(size_t)(n0 + c) * K + k4 * 4]);
        Ws[(k4 * 4 + 0) * WP + c] = w.x;
        Ws[(k4 * 4 + 1) * WP + c] = w.y;
        Ws[(k4 * 4 + 2) * WP + c] = w.z;
        Ws[(k4 * 4 + 3) * WP + c] = w.w;
    }
    // stage A tile (row-major, padded stride)
    for (int i = tid; i < BM * (K / 4); i += 256) {
        int r = i / (K / 4);
        int k4 = i - r * (K / 4);
        *reinterpret_cast<float4*>(&As[r * KP + k4 * 4]) =
            *reinterpret_cast<const float4*>(&in[(size_t)(row0 + r) * K + k4 * 4]);
    }
    __syncthreads();
    if (tid < CT * RT) {
        int ty = tid / CT, tx = tid - (tid / CT) * CT;
        int r0 = ty * TM, c0 = tx * TN;
        float acc[TM][TN];
#pragma unroll
        for (int i = 0; i < TM; ++i)
#pragma unroll
            for (int c = 0; c < TN; ++c) acc[i][c] = 0.f;
        for (int k = 0; k < K; k += 4) {
            float4 a[TM];
#pragma unroll
            for (int i = 0; i < TM; ++i)
                a[i] = *reinterpret_cast<const float4*>(&As[(r0 + i) * KP + k]);
            float bv[4][TN];
#pragma unroll
            for (int j = 0; j < 4; ++j)
#pragma unroll
                for (int c = 0; c < TN; ++c) bv[j][c] = Ws[(k + j) * WP + c0 + c];
#pragma unroll
            for (int i = 0; i < TM; ++i)
#pragma unroll
                for (int c = 0; c < TN; ++c)
                    acc[i][c] += a[i].x * bv[0][c] + a[i].y * bv[1][c]
                               + a[i].z * bv[2][c] + a[i].w * bv[3][c];
        }
#pragma unroll
        for (int i = 0; i < TM; ++i) {
            size_t o = (size_t)(row0 + r0 + i) * Nfull + n0 + c0;
            if constexpr (TN == 4) {
                float4 v = {acc[i][0], acc[i][1], acc[i][2], acc[i][3]};
                *reinterpret_cast<float4*>(&out[o]) = v;
            } else {
#pragma unroll
                for (int c = 0; c < TN; ++c) out[o + c] = acc[i][c];
            }
        }
    }
}

// ----------- causal depthwise conv (K=4) + SiLU: u[b,t,d] -----------------------
__global__ __launch_bounds__(256) void k_conv(const float* __restrict__ xz,
                                              const float* __restrict__ cw,
                                              const float* __restrict__ cb,
                                              float* __restrict__ u) {
    int idx = blockIdx.x * 256 + threadIdx.x;          // over BL*DI
    if (idx >= BL * DI) return;
    int d = idx & 127;
    int bl = idx >> 7;
    int b = bl >> 12;
    int t = bl & 4095;
    float acc = cb[d];
    const float* xp = xz + ((size_t)b * HW) * 256 + d; // u-half column d
#pragma unroll
    for (int k = 0; k < 4; ++k) {
        int tt = t - 3 + k;
        if (tt >= 0) acc += cw[d * 4 + k] * xp[(size_t)tt * 256];
    }
    u[idx] = acc * sigmoid_f(acc);
}

// ---------------- scan pass 1: per-chunk local scan (h0 = 0) -------------------
__global__ __launch_bounds__(128) void k_scan1(const float* __restrict__ u,
                                               const float* __restrict__ xdbl,
                                               const float* __restrict__ dpw,
                                               const float* __restrict__ dpb,
                                               const float* __restrict__ Alog,
                                               float* __restrict__ cS,
                                               float* __restrict__ cDT) {
    int blk = blockIdx.x;   // b*NC + c
    int b = blk >> 6;
    int c = blk & (NC - 1);
    int d = threadIdx.x;
    float a[NS];
#pragma unroll
    for (int n = 0; n < NS; ++n) a[n] = -__expf(Alog[d * NS + n]);
    float w0 = dpw[d * 4 + 0], w1 = dpw[d * 4 + 1],
          w2 = dpw[d * 4 + 2], w3 = dpw[d * 4 + 3];
    float bb = dpb[d];
    float h[NS];
#pragma unroll
    for (int n = 0; n < NS; ++n) h[n] = 0.f;
    float sdt = 0.f;
    int t0 = c * CS;
    for (int tt = 0; tt < CS; ++tt) {
        size_t base = (size_t)b * HW + t0 + tt;
        const float* xd = xdbl + base * 36;
        float dt = softplus_f(w0 * xd[0] + w1 * xd[1] + w2 * xd[2] + w3 * xd[3] + bb);
        float uu = u[base * DI + d];
        float du = dt * uu;
        sdt += dt;
#pragma unroll
        for (int n = 0; n < NS; ++n) {
            float dA = __expf(dt * a[n]);
            h[n] = dA * h[n] + du * xd[4 + n];
        }
    }
    size_t o = (size_t)blk * DI + d;
    cDT[o] = sdt;
#pragma unroll
    for (int n = 0; n < NS; ++n) cS[o * NS + n] = h[n];
}

// ------------- scan pass 2: sequential chunk combine per (b,d,n) ---------------
__global__ __launch_bounds__(256) void k_scan2(const float* __restrict__ cS,
                                               const float* __restrict__ cDT,
                                               const float* __restrict__ Alog,
                                               float* __restrict__ iS) {
    int idx = blockIdx.x * 256 + threadIdx.x;          // over Bn*DI*NS
    if (idx >= Bn * DI * NS) return;
    int n = idx & 15;
    int d = (idx >> 4) & 127;
    int b = idx >> 11;
    float a = -__expf(Alog[d * NS + n]);
    float h = 0.f;
    for (int c = 0; c < NC; ++c) {
        size_t o = (size_t)(b * NC + c) * DI + d;
        iS[o * NS + n] = h;
        h = __expf(a * cDT[o]) * h + cS[o * NS + n];
    }
}

// ------- scan pass 3: re-scan with proper h0, emit gated y (overwrites u) ------
__global__ __launch_bounds__(128) void k_scan3(float* __restrict__ uy,
                                               const float* __restrict__ xz,
                                               const float* __restrict__ xdbl,
                                               const float* __restrict__ dpw,
                                               const float* __restrict__ dpb,
                                               const float* __restrict__ Alog,
                                               const float* __restrict__ Dp,
                                               const float* __restrict__ iS) {
    int blk = blockIdx.x;
    int b = blk >> 6;
    int c = blk & (NC - 1);
    int d = threadIdx.x;
    float a[NS];
#pragma unroll
    for (int n = 0; n < NS; ++n) a[n] = -__expf(Alog[d * NS + n]);
    float w0 = dpw[d * 4 + 0], w1 = dpw[d * 4 + 1],
          w2 = dpw[d * 4 + 2], w3 = dpw[d * 4 + 3];
    float bb = dpb[d];
    float Dv = Dp[d];
    float h[NS];
    size_t so = (size_t)blk * DI + d;
#pragma unroll
    for (int n = 0; n < NS; ++n) h[n] = iS[so * NS + n];
    int t0 = c * CS;
    for (int tt = 0; tt < CS; ++tt) {
        size_t base = (size_t)b * HW + t0 + tt;
        const float* xd = xdbl + base * 36;
        float dt = softplus_f(w0 * xd[0] + w1 * xd[1] + w2 * xd[2] + w3 * xd[3] + bb);
        float uu = uy[base * DI + d];
        float du = dt * uu;
        float y = 0.f;
#pragma unroll
        for (int n = 0; n < NS; ++n) {
            float dA = __expf(dt * a[n]);
            h[n] = dA * h[n] + du * xd[4 + n];
            y += h[n] * xd[20 + n];
        }
        y += uu * Dv;
        float zz = xz[base * 256 + 128 + d];
        y *= zz * sigmoid_f(zz);
        uy[base * DI + d] = y;
    }
}

// ---------------- layernorm over last dim (64), in place -----------------------
__global__ __launch_bounds__(256) void k_ln(float* __restrict__ feat,
                                            const float* __restrict__ g,
                                            const float* __restrict__ bta, int R) {
    int lane = threadIdx.x & 63;
    int wv = blockIdx.x * 4 + (threadIdx.x >> 6);
    int stride = gridDim.x * 4;
    for (int row = wv; row < R; row += stride) {
        float x = feat[(size_t)row * 64 + lane];
        float s = x;
#pragma unroll
        for (int off = 32; off; off >>= 1) s += __shfl_xor(s, off, 64);
        float mu = s * (1.f / 64.f);
        float xm = x - mu;
        float v = xm * xm;
#pragma unroll
        for (int off = 32; off; off >>= 1) v += __shfl_xor(v, off, 64);
        float var = v * (1.f / 64.f);
        feat[(size_t)row * 64 + lane] = xm * rsqrtf(var + 1e-5f) * g[lane] + bta[lane];
    }
}

// ---------------- head + residual: out = z - (feat @ head_w.T + head_b) --------
__global__ __launch_bounds__(256) void k_head(const float* __restrict__ feat,
                                              const float* __restrict__ hwt,
                                              const float* __restrict__ hb,
                                              const float* __restrict__ z,
                                              float* __restrict__ out) {
    __shared__ float fl[64 * 65];
    int row0 = blockIdx.x * 64;
    for (int i = threadIdx.x; i < 64 * 64; i += 256) {
        int r = i >> 6;
        int m = i & 63;
        fl[r * 65 + m] = feat[(size_t)(row0 + r) * 64 + m];
    }
    __syncthreads();
    int r = threadIdx.x >> 2;
    int c = threadIdx.x & 3;
    float acc = hb[c];
#pragma unroll
    for (int m = 0; m < 64; ++m) acc += fl[r * 65 + m] * hwt[c * 64 + m];
    int bl = row0 + r;
    int b = bl >> 12;
    int hw = bl & 4095;
    size_t o = ((size_t)b * 4 + c) * HW + hw;
    out[o] = z[o] - acc;
}

// -------------------------------------------------------------------------------
static void run_mamba(const float* const* P, float* feat, float* xz, float* u,
                      float* xdbl, float* cS, float* cDT, float* iS,
                      hipStream_t s) {
    // P: 0 in_proj_w, 1 conv_w, 2 conv_b, 3 x_proj_w, 4 dt_proj_w, 5 dt_proj_b,
    //    6 A_log, 7 D, 8 out_proj_w
    k_gemm<64, 64, 4><<<dim3(BL / 64, 4), 256, 0, s>>>(feat, P[0], xz, 256);
    k_conv<<<(BL * DI) / 256, 256, 0, s>>>(xz, P[1], P[2], u);
    k_gemm<128, 36, 3><<<dim3(BL / 64, 1), 256, 0, s>>>(u, P[3], xdbl, 36);
    k_scan1<<<Bn * NC, DI, 0, s>>>(u, xdbl, P[4], P[5], P[6], cS, cDT);
    k_scan2<<<(Bn * DI * NS) / 256, 256, 0, s>>>(cS, cDT, P[6], iS);
    k_scan3<<<Bn * NC, DI, 0, s>>>(u, xz, xdbl, P[4], P[5], P[6], P[7], iS);
    k_gemm<128, 64, 4><<<dim3(BL / 64, 1), 256, 0, s>>>(u, P[8], feat, 64);
}

extern "C" void kernel_launch(void* const* d_in, const int* in_sizes, int n_in,
                              void* d_out, int out_size, void* d_ws, size_t ws_size,
                              hipStream_t stream) {
    const float* z = (const float*)d_in[0];
    const float* ew = (const float*)d_in[1];
    const float* eb = (const float*)d_in[2];
    const float* m1[9];
    const float* m2[9];
    for (int i = 0; i < 9; ++i) m1[i] = (const float*)d_in[3 + i];
    for (int i = 0; i < 9; ++i) m2[i] = (const float*)d_in[12 + i];
    const float* ln1g = (const float*)d_in[21];
    const float* ln1b = (const float*)d_in[22];
    const float* ln2g = (const float*)d_in[23];
    const float* ln2b = (const float*)d_in[24];
    const float* hwt = (const float*)d_in[25];
    const float* hb = (const float*)d_in[26];

    float* ws = (float*)d_ws;
    float* feat = ws;                         // BL*64
    float* xz = feat + (size_t)BL * 64;       // BL*256
    float* u = xz + (size_t)BL * 256;         // BL*128
    float* xdbl = u + (size_t)BL * 128;       // BL*36
    float* cS = xdbl + (size_t)BL * 36;       // Bn*NC*DI*NS
    float* cDT = cS + (size_t)Bn * NC * DI * NS;  // Bn*NC*DI
    float* iS = cDT + (size_t)Bn * NC * DI;   // Bn*NC*DI*NS

    k_embed<<<(BL * DM) / 256, 256, 0, stream>>>(z, ew, eb, feat);

    run_mamba(m1, feat, xz, u, xdbl, cS, cDT, iS, stream);
    k_ln<<<4096, 256, 0, stream>>>(feat, ln1g, ln1b, BL);
    run_mamba(m2, feat, xz, u, xdbl, cS, cDT, iS, stream);
    k_ln<<<4096, 256, 0, stream>>>(feat, ln2g, ln2b, BL);

    k_head<<<BL / 64, 256, 0, stream>>>(feat, hwt, hb, z, (float*)d_out);
}

// Round 6
// 703.152 us; speedup vs baseline: 1.5644x; 1.0887x over previous
//
#include <hip/hip_runtime.h>
#include <hip/hip_bf16.h>

#define DEV __device__ __forceinline__

static constexpr int Bn = 16;
static constexpr int Cc = 4;
static constexpr int HW = 4096;      // L (=64*64)
static constexpr int BL = Bn * HW;   // 65536 rows
static constexpr int DM = 64;
static constexpr int DI = 128;
static constexpr int NS = 16;        // D_STATE
static constexpr int NC = 128;       // chunks per sequence (16 waves/CU in scans)
static constexpr int CS = HW / NC;   // 32 steps per chunk

DEV float softplus_f(float x) { return fmaxf(x, 0.f) + log1pf(__expf(-fabsf(x))); }
DEV float sigmoid_f(float x) { return 1.f / (1.f + __expf(-x)); }

// ---------------- embed: feat[b,l,m] = sum_c z[b,c,l]*ew[m,c] + eb[m] ----------
__global__ __launch_bounds__(256) void k_embed(const float* __restrict__ z,
                                               const float* __restrict__ ew,
                                               const float* __restrict__ eb,
                                               float* __restrict__ feat) {
    int idx = blockIdx.x * 256 + threadIdx.x;          // over BL*DM
    if (idx >= BL * DM) return;
    int m = idx & 63;
    int bl = idx >> 6;
    int b = bl >> 12;
    int hw = bl & 4095;
    const float* zp = z + (size_t)b * Cc * HW + hw;
    float acc = eb[m];
#pragma unroll
    for (int c = 0; c < 4; ++c) acc += zp[(size_t)c * HW] * ew[m * 4 + c];
    feat[idx] = acc;
}

// ---- register-tiled GEMM: out[r, n0+c] = sum_k in[r,k] * W[n0+c, k] -----------
template <int K, int BN, int TN>
__global__ __launch_bounds__(256) void k_gemm(const float* __restrict__ in,
                                              const float* __restrict__ W,
                                              float* __restrict__ out,
                                              int Nfull) {
    constexpr int BM = 64, TM = 4;
    constexpr int CT = BN / TN;        // threads along cols
    constexpr int RT = BM / TM;        // 16 threads along rows
    constexpr int KP = K + 4;          // A row stride
    constexpr int WP = BN + 4;         // Ws row stride
    __shared__ float As[BM * KP];
    __shared__ float Ws[K * WP];
    int tid = threadIdx.x;
    int n0 = blockIdx.y * BN;
    int row0 = blockIdx.x * BM;
    for (int i = tid; i < BN * (K / 4); i += 256) {
        int c = i / (K / 4);
        int k4 = i - c * (K / 4);
        float4 w = *reinterpret_cast<const float4*>(&W[(size_t)(n0 + c) * K + k4 * 4]);
        Ws[(k4 * 4 + 0) * WP + c] = w.x;
        Ws[(k4 * 4 + 1) * WP + c] = w.y;
        Ws[(k4 * 4 + 2) * WP + c] = w.z;
        Ws[(k4 * 4 + 3) * WP + c] = w.w;
    }
    for (int i = tid; i < BM * (K / 4); i += 256) {
        int r = i / (K / 4);
        int k4 = i - r * (K / 4);
        *reinterpret_cast<float4*>(&As[r * KP + k4 * 4]) =
            *reinterpret_cast<const float4*>(&in[(size_t)(row0 + r) * K + k4 * 4]);
    }
    __syncthreads();
    if (tid < CT * RT) {
        int ty = tid / CT, tx = tid - (tid / CT) * CT;
        int r0 = ty * TM, c0 = tx * TN;
        float acc[TM][TN];
#pragma unroll
        for (int i = 0; i < TM; ++i)
#pragma unroll
            for (int c = 0; c < TN; ++c) acc[i][c] = 0.f;
        for (int k = 0; k < K; k += 4) {
            float4 a[TM];
#pragma unroll
            for (int i = 0; i < TM; ++i)
                a[i] = *reinterpret_cast<const float4*>(&As[(r0 + i) * KP + k]);
            float bv[4][TN];
#pragma unroll
            for (int j = 0; j < 4; ++j)
#pragma unroll
                for (int c = 0; c < TN; ++c) bv[j][c] = Ws[(k + j) * WP + c0 + c];
#pragma unroll
            for (int i = 0; i < TM; ++i)
#pragma unroll
                for (int c = 0; c < TN; ++c)
                    acc[i][c] += a[i].x * bv[0][c] + a[i].y * bv[1][c]
                               + a[i].z * bv[2][c] + a[i].w * bv[3][c];
        }
#pragma unroll
        for (int i = 0; i < TM; ++i) {
            size_t o = (size_t)(row0 + r0 + i) * Nfull + n0 + c0;
            if constexpr (TN == 4) {
                float4 v = {acc[i][0], acc[i][1], acc[i][2], acc[i][3]};
                *reinterpret_cast<float4*>(&out[o]) = v;
            } else {
#pragma unroll
                for (int c = 0; c < TN; ++c) out[o + c] = acc[i][c];
            }
        }
    }
}

// ----------- causal depthwise conv (K=4) + SiLU: u[b,t,d] -----------------------
__global__ __launch_bounds__(256) void k_conv(const float* __restrict__ xz,
                                              const float* __restrict__ cw,
                                              const float* __restrict__ cb,
                                              float* __restrict__ u) {
    int idx = blockIdx.x * 256 + threadIdx.x;          // over BL*DI
    if (idx >= BL * DI) return;
    int d = idx & 127;
    int bl = idx >> 7;
    int b = bl >> 12;
    int t = bl & 4095;
    float acc = cb[d];
    const float* xp = xz + ((size_t)b * HW) * 256 + d; // u-half column d
#pragma unroll
    for (int k = 0; k < 4; ++k) {
        int tt = t - 3 + k;
        if (tt >= 0) acc += cw[d * 4 + k] * xp[(size_t)tt * 256];
    }
    u[idx] = acc * sigmoid_f(acc);
}

// 4-component SSM update: h = exp(dt*a)*h + du*Bv
#define UPD4(H, A, BV)                                   \
    H.x = __expf(dt * A.x) * H.x + du * BV.x;            \
    H.y = __expf(dt * A.y) * H.y + du * BV.y;            \
    H.z = __expf(dt * A.z) * H.z + du * BV.z;            \
    H.w = __expf(dt * A.w) * H.w + du * BV.w;

// ---------------- scan pass 1: per-chunk local scan (h0 = 0) -------------------
__global__ __launch_bounds__(128, 4) void k_scan1(const float* __restrict__ u,
                                                  const float* __restrict__ xdbl,
                                                  const float* __restrict__ dpw,
                                                  const float* __restrict__ dpb,
                                                  const float* __restrict__ Alog,
                                                  float* __restrict__ cS,
                                                  float* __restrict__ cDT) {
    int blk = blockIdx.x;   // b*NC + c
    int b = blk / NC;
    int c = blk % NC;
    int d = threadIdx.x;
    const float4* al = reinterpret_cast<const float4*>(Alog + d * NS);
    float4 t0v = al[0], t1v = al[1], t2v = al[2], t3v = al[3];
    float4 a0, a1, a2, a3;
    a0.x = -__expf(t0v.x); a0.y = -__expf(t0v.y); a0.z = -__expf(t0v.z); a0.w = -__expf(t0v.w);
    a1.x = -__expf(t1v.x); a1.y = -__expf(t1v.y); a1.z = -__expf(t1v.z); a1.w = -__expf(t1v.w);
    a2.x = -__expf(t2v.x); a2.y = -__expf(t2v.y); a2.z = -__expf(t2v.z); a2.w = -__expf(t2v.w);
    a3.x = -__expf(t3v.x); a3.y = -__expf(t3v.y); a3.z = -__expf(t3v.z); a3.w = -__expf(t3v.w);
    float4 w = *reinterpret_cast<const float4*>(dpw + d * 4);
    float bb = dpb[d];
    float4 h0 = {0, 0, 0, 0}, h1 = {0, 0, 0, 0}, h2 = {0, 0, 0, 0}, h3 = {0, 0, 0, 0};
    float sdt = 0.f;
    int t0 = c * CS;
    for (int tt = 0; tt < CS; ++tt) {
        size_t base = (size_t)b * HW + t0 + tt;
        const float4* xd4 = reinterpret_cast<const float4*>(xdbl + base * 36);
        float4 x0 = xd4[0];
        float4 B0 = xd4[1], B1 = xd4[2], B2 = xd4[3], B3 = xd4[4];
        float dt = softplus_f(w.x * x0.x + w.y * x0.y + w.z * x0.z + w.w * x0.w + bb);
        float uu = u[base * DI + d];
        float du = dt * uu;
        sdt += dt;
        UPD4(h0, a0, B0) UPD4(h1, a1, B1) UPD4(h2, a2, B2) UPD4(h3, a3, B3)
    }
    size_t o = (size_t)blk * DI + d;
    cDT[o] = sdt;
    float4* cs4 = reinterpret_cast<float4*>(cS + o * NS);
    cs4[0] = h0; cs4[1] = h1; cs4[2] = h2; cs4[3] = h3;
}

// ------ scan pass 2: sequential chunk combine per (b,d,n), IN PLACE on cS ------
// After this kernel, cS[b,c,d,n] holds the INITIAL state for chunk c.
__global__ __launch_bounds__(256) void k_scan2(float* __restrict__ cS,
                                               const float* __restrict__ cDT,
                                               const float* __restrict__ Alog) {
    int idx = blockIdx.x * 256 + threadIdx.x;          // over Bn*DI*NS
    if (idx >= Bn * DI * NS) return;
    int n = idx & 15;
    int d = (idx >> 4) & 127;
    int b = idx >> 11;
    float a = -__expf(Alog[d * NS + n]);
    float h = 0.f;
    for (int c = 0; c < NC; ++c) {
        size_t o = (size_t)(b * NC + c) * DI + d;
        float s = cS[o * NS + n];
        cS[o * NS + n] = h;
        h = __expf(a * cDT[o]) * h + s;
    }
}

// ------- scan pass 3: re-scan with proper h0, emit gated y (overwrites u) ------
__global__ __launch_bounds__(128, 4) void k_scan3(float* __restrict__ uy,
                                                  const float* __restrict__ xz,
                                                  const float* __restrict__ xdbl,
                                                  const float* __restrict__ dpw,
                                                  const float* __restrict__ dpb,
                                                  const float* __restrict__ Alog,
                                                  const float* __restrict__ Dp,
                                                  const float* __restrict__ iS) {
    int blk = blockIdx.x;
    int b = blk / NC;
    int c = blk % NC;
    int d = threadIdx.x;
    const float4* al = reinterpret_cast<const float4*>(Alog + d * NS);
    float4 t0v = al[0], t1v = al[1], t2v = al[2], t3v = al[3];
    float4 a0, a1, a2, a3;
    a0.x = -__expf(t0v.x); a0.y = -__expf(t0v.y); a0.z = -__expf(t0v.z); a0.w = -__expf(t0v.w);
    a1.x = -__expf(t1v.x); a1.y = -__expf(t1v.y); a1.z = -__expf(t1v.z); a1.w = -__expf(t1v.w);
    a2.x = -__expf(t2v.x); a2.y = -__expf(t2v.y); a2.z = -__expf(t2v.z); a2.w = -__expf(t2v.w);
    a3.x = -__expf(t3v.x); a3.y = -__expf(t3v.y); a3.z = -__expf(t3v.z); a3.w = -__expf(t3v.w);
    float4 w = *reinterpret_cast<const float4*>(dpw + d * 4);
    float bb = dpb[d];
    float Dv = Dp[d];
    size_t so = (size_t)blk * DI + d;
    const float4* is4 = reinterpret_cast<const float4*>(iS + so * NS);
    float4 h0 = is4[0], h1 = is4[1], h2 = is4[2], h3 = is4[3];
    int t0 = c * CS;
    for (int tt = 0; tt < CS; ++tt) {
        size_t base = (size_t)b * HW + t0 + tt;
        const float4* xd4 = reinterpret_cast<const float4*>(xdbl + base * 36);
        float4 x0 = xd4[0];
        float4 B0 = xd4[1], B1 = xd4[2], B2 = xd4[3], B3 = xd4[4];
        float4 C0 = xd4[5], C1 = xd4[6], C2 = xd4[7], C3 = xd4[8];
        float dt = softplus_f(w.x * x0.x + w.y * x0.y + w.z * x0.z + w.w * x0.w + bb);
        float uu = uy[base * DI + d];
        float du = dt * uu;
        UPD4(h0, a0, B0) UPD4(h1, a1, B1) UPD4(h2, a2, B2) UPD4(h3, a3, B3)
        float y = h0.x * C0.x + h0.y * C0.y + h0.z * C0.z + h0.w * C0.w
                + h1.x * C1.x + h1.y * C1.y + h1.z * C1.z + h1.w * C1.w
                + h2.x * C2.x + h2.y * C2.y + h2.z * C2.z + h2.w * C2.w
                + h3.x * C3.x + h3.y * C3.y + h3.z * C3.z + h3.w * C3.w;
        y += uu * Dv;
        float zz = xz[base * 256 + 128 + d];
        y *= zz * sigmoid_f(zz);
        uy[base * DI + d] = y;
    }
}

// ---------------- layernorm over last dim (64), in place -----------------------
__global__ __launch_bounds__(256) void k_ln(float* __restrict__ feat,
                                            const float* __restrict__ g,
                                            const float* __restrict__ bta, int R) {
    int lane = threadIdx.x & 63;
    int wv = blockIdx.x * 4 + (threadIdx.x >> 6);
    int stride = gridDim.x * 4;
    for (int row = wv; row < R; row += stride) {
        float x = feat[(size_t)row * 64 + lane];
        float s = x;
#pragma unroll
        for (int off = 32; off; off >>= 1) s += __shfl_xor(s, off, 64);
        float mu = s * (1.f / 64.f);
        float xm = x - mu;
        float v = xm * xm;
#pragma unroll
        for (int off = 32; off; off >>= 1) v += __shfl_xor(v, off, 64);
        float var = v * (1.f / 64.f);
        feat[(size_t)row * 64 + lane] = xm * rsqrtf(var + 1e-5f) * g[lane] + bta[lane];
    }
}

// ---------------- head + residual: out = z - (feat @ head_w.T + head_b) --------
__global__ __launch_bounds__(256) void k_head(const float* __restrict__ feat,
                                              const float* __restrict__ hwt,
                                              const float* __restrict__ hb,
                                              const float* __restrict__ z,
                                              float* __restrict__ out) {
    __shared__ float fl[64 * 65];
    int row0 = blockIdx.x * 64;
    for (int i = threadIdx.x; i < 64 * 64; i += 256) {
        int r = i >> 6;
        int m = i & 63;
        fl[r * 65 + m] = feat[(size_t)(row0 + r) * 64 + m];
    }
    __syncthreads();
    int r = threadIdx.x >> 2;
    int c = threadIdx.x & 3;
    float acc = hb[c];
#pragma unroll
    for (int m = 0; m < 64; ++m) acc += fl[r * 65 + m] * hwt[c * 64 + m];
    int bl = row0 + r;
    int b = bl >> 12;
    int hw = bl & 4095;
    size_t o = ((size_t)b * 4 + c) * HW + hw;
    out[o] = z[o] - acc;
}

// -------------------------------------------------------------------------------
static void run_mamba(const float* const* P, float* feat, float* xz, float* u,
                      float* xdbl, float* cS, float* cDT, hipStream_t s) {
    // P: 0 in_proj_w, 1 conv_w, 2 conv_b, 3 x_proj_w, 4 dt_proj_w, 5 dt_proj_b,
    //    6 A_log, 7 D, 8 out_proj_w
    k_gemm<64, 64, 4><<<dim3(BL / 64, 4), 256, 0, s>>>(feat, P[0], xz, 256);
    k_conv<<<(BL * DI) / 256, 256, 0, s>>>(xz, P[1], P[2], u);
    k_gemm<128, 36, 3><<<dim3(BL / 64, 1), 256, 0, s>>>(u, P[3], xdbl, 36);
    k_scan1<<<Bn * NC, DI, 0, s>>>(u, xdbl, P[4], P[5], P[6], cS, cDT);
    k_scan2<<<(Bn * DI * NS) / 256, 256, 0, s>>>(cS, cDT, P[6]);
    k_scan3<<<Bn * NC, DI, 0, s>>>(u, xz, xdbl, P[4], P[5], P[6], P[7], cS);
    k_gemm<128, 64, 4><<<dim3(BL / 64, 1), 256, 0, s>>>(u, P[8], feat, 64);
}

extern "C" void kernel_launch(void* const* d_in, const int* in_sizes, int n_in,
                              void* d_out, int out_size, void* d_ws, size_t ws_size,
                              hipStream_t stream) {
    const float* z = (const float*)d_in[0];
    const float* ew = (const float*)d_in[1];
    const float* eb = (const float*)d_in[2];
    const float* m1[9];
    const float* m2[9];
    for (int i = 0; i < 9; ++i) m1[i] = (const float*)d_in[3 + i];
    for (int i = 0; i < 9; ++i) m2[i] = (const float*)d_in[12 + i];
    const float* ln1g = (const float*)d_in[21];
    const float* ln1b = (const float*)d_in[22];
    const float* ln2g = (const float*)d_in[23];
    const float* ln2b = (const float*)d_in[24];
    const float* hwt = (const float*)d_in[25];
    const float* hb = (const float*)d_in[26];

    float* ws = (float*)d_ws;
    float* feat = ws;                         // BL*64
    float* xz = feat + (size_t)BL * 64;       // BL*256
    float* u = xz + (size_t)BL * 256;         // BL*128
    float* xdbl = u + (size_t)BL * 128;       // BL*36
    float* cS = xdbl + (size_t)BL * 36;       // Bn*NC*DI*NS
    float* cDT = cS + (size_t)Bn * NC * DI * NS;  // Bn*NC*DI

    k_embed<<<(BL * DM) / 256, 256, 0, stream>>>(z, ew, eb, feat);

    run_mamba(m1, feat, xz, u, xdbl, cS, cDT, stream);
    k_ln<<<4096, 256, 0, stream>>>(feat, ln1g, ln1b, BL);
    run_mamba(m2, feat, xz, u, xdbl, cS, cDT, stream);
    k_ln<<<4096, 256, 0, stream>>>(feat, ln2g, ln2b, BL);

    k_head<<<BL / 64, 256, 0, stream>>>(feat, hwt, hb, z, (float*)d_out);
}

// Round 7
// 563.962 us; speedup vs baseline: 1.9505x; 1.2468x over previous
//
#include <hip/hip_runtime.h>
#include <hip/hip_bf16.h>

#define DEV __device__ __forceinline__

static constexpr int Bn = 16;
static constexpr int Cc = 4;
static constexpr int HW = 4096;      // L (=64*64)
static constexpr int BL = Bn * HW;   // 65536 rows
static constexpr int DM = 64;
static constexpr int DI = 128;
static constexpr int NS = 16;        // D_STATE
static constexpr int NC = 256;       // chunks per sequence (full wave occupancy)
static constexpr int CS = HW / NC;   // 16 steps per chunk

DEV float sigmoid_f(float x) { return 1.f / (1.f + __expf(-x)); }
// fast softplus: v_exp + v_log instead of library log1pf
DEV float softplus_f(float x) {
    return fmaxf(x, 0.f) + __logf(1.f + __expf(-fabsf(x)));
}

// ---------------- embed: feat[b,l,m] = sum_c z[b,c,l]*ew[m,c] + eb[m] ----------
__global__ __launch_bounds__(256) void k_embed(const float* __restrict__ z,
                                               const float* __restrict__ ew,
                                               const float* __restrict__ eb,
                                               float* __restrict__ feat) {
    int idx = blockIdx.x * 256 + threadIdx.x;          // over BL*DM
    if (idx >= BL * DM) return;
    int m = idx & 63;
    int bl = idx >> 6;
    int b = bl >> 12;
    int hw = bl & 4095;
    const float* zp = z + (size_t)b * Cc * HW + hw;
    float acc = eb[m];
#pragma unroll
    for (int c = 0; c < 4; ++c) acc += zp[(size_t)c * HW] * ew[m * 4 + c];
    feat[idx] = acc;
}

// ---- register-tiled GEMM: out[r, n0+c] = sum_k in[r,k] * W[n0+c, k] -----------
template <int K, int BN, int TN>
__global__ __launch_bounds__(256) void k_gemm(const float* __restrict__ in,
                                              const float* __restrict__ W,
                                              float* __restrict__ out,
                                              int Nfull) {
    constexpr int BM = 64, TM = 4;
    constexpr int CT = BN / TN;        // threads along cols
    constexpr int RT = BM / TM;        // 16 threads along rows
    constexpr int KP = K + 4;          // A row stride
    constexpr int WP = BN + 4;         // Ws row stride
    __shared__ float As[BM * KP];
    __shared__ float Ws[K * WP];
    int tid = threadIdx.x;
    int n0 = blockIdx.y * BN;
    int row0 = blockIdx.x * BM;
    for (int i = tid; i < BN * (K / 4); i += 256) {
        int c = i / (K / 4);
        int k4 = i - c * (K / 4);
        float4 w = *reinterpret_cast<const float4*>(&W[(size_t)(n0 + c) * K + k4 * 4]);
        Ws[(k4 * 4 + 0) * WP + c] = w.x;
        Ws[(k4 * 4 + 1) * WP + c] = w.y;
        Ws[(k4 * 4 + 2) * WP + c] = w.z;
        Ws[(k4 * 4 + 3) * WP + c] = w.w;
    }
    for (int i = tid; i < BM * (K / 4); i += 256) {
        int r = i / (K / 4);
        int k4 = i - r * (K / 4);
        *reinterpret_cast<float4*>(&As[r * KP + k4 * 4]) =
            *reinterpret_cast<const float4*>(&in[(size_t)(row0 + r) * K + k4 * 4]);
    }
    __syncthreads();
    if (tid < CT * RT) {
        int ty = tid / CT, tx = tid - (tid / CT) * CT;
        int r0 = ty * TM, c0 = tx * TN;
        float acc[TM][TN];
#pragma unroll
        for (int i = 0; i < TM; ++i)
#pragma unroll
            for (int c = 0; c < TN; ++c) acc[i][c] = 0.f;
        for (int k = 0; k < K; k += 4) {
            float4 a[TM];
#pragma unroll
            for (int i = 0; i < TM; ++i)
                a[i] = *reinterpret_cast<const float4*>(&As[(r0 + i) * KP + k]);
            float bv[4][TN];
#pragma unroll
            for (int j = 0; j < 4; ++j)
#pragma unroll
                for (int c = 0; c < TN; ++c) bv[j][c] = Ws[(k + j) * WP + c0 + c];
#pragma unroll
            for (int i = 0; i < TM; ++i)
#pragma unroll
                for (int c = 0; c < TN; ++c)
                    acc[i][c] += a[i].x * bv[0][c] + a[i].y * bv[1][c]
                               + a[i].z * bv[2][c] + a[i].w * bv[3][c];
        }
#pragma unroll
        for (int i = 0; i < TM; ++i) {
            size_t o = (size_t)(row0 + r0 + i) * Nfull + n0 + c0;
            if constexpr (TN == 4) {
                float4 v = {acc[i][0], acc[i][1], acc[i][2], acc[i][3]};
                *reinterpret_cast<float4*>(&out[o]) = v;
            } else {
#pragma unroll
                for (int c = 0; c < TN; ++c) out[o + c] = acc[i][c];
            }
        }
    }
}

// ----------- causal depthwise conv (K=4) + SiLU: u[b,t,d] -----------------------
__global__ __launch_bounds__(256) void k_conv(const float* __restrict__ xz,
                                              const float* __restrict__ cw,
                                              const float* __restrict__ cb,
                                              float* __restrict__ u) {
    int idx = blockIdx.x * 256 + threadIdx.x;          // over BL*DI
    if (idx >= BL * DI) return;
    int d = idx & 127;
    int bl = idx >> 7;
    int b = bl >> 12;
    int t = bl & 4095;
    float acc = cb[d];
    const float* xp = xz + ((size_t)b * HW) * 256 + d; // u-half column d
#pragma unroll
    for (int k = 0; k < 4; ++k) {
        int tt = t - 3 + k;
        if (tt >= 0) acc += cw[d * 4 + k] * xp[(size_t)tt * 256];
    }
    u[idx] = acc * sigmoid_f(acc);
}

// ---- helpers for the scan kernels --------------------------------------------
// load a-vector, detect a_n == a0*(n+1) structure (A_log = log(arange(1..16)))
DEV bool load_a_struct(const float* Alog, int d, float4& a0v, float4& a1v,
                       float4& a2v, float4& a3v, float& a0) {
    const float4* al = reinterpret_cast<const float4*>(Alog + d * NS);
    float4 t0 = al[0], t1 = al[1], t2 = al[2], t3 = al[3];
    a0v.x = -__expf(t0.x); a0v.y = -__expf(t0.y); a0v.z = -__expf(t0.z); a0v.w = -__expf(t0.w);
    a1v.x = -__expf(t1.x); a1v.y = -__expf(t1.y); a1v.z = -__expf(t1.z); a1v.w = -__expf(t1.w);
    a2v.x = -__expf(t2.x); a2v.y = -__expf(t2.y); a2v.z = -__expf(t2.z); a2v.w = -__expf(t2.w);
    a3v.x = -__expf(t3.x); a3v.y = -__expf(t3.y); a3v.z = -__expf(t3.z); a3v.w = -__expf(t3.w);
    a0 = a0v.x;
    float aa[16] = {a0v.x, a0v.y, a0v.z, a0v.w, a1v.x, a1v.y, a1v.z, a1v.w,
                    a2v.x, a2v.y, a2v.z, a2v.w, a3v.x, a3v.y, a3v.z, a3v.w};
    bool fast = true;
#pragma unroll
    for (int n = 0; n < 16; ++n)
        fast = fast && (fabsf(aa[n] - a0 * (float)(n + 1)) <= 1e-4f * (float)(n + 1));
    return fast;
}

// compute E1^(1..16) into 4 float4s, E1 = exp(dt*a0); tree of 15 muls
#define POWERS(dt, a0, D0, D1, D2, D3)                        \
    {                                                         \
        float E1 = __expf((dt) * (a0));                       \
        float E2 = E1 * E1, E3 = E2 * E1, E4 = E2 * E2;       \
        float E5 = E3 * E2, E6 = E3 * E3, E7 = E4 * E3;       \
        float E8 = E4 * E4, E9 = E5 * E4, E10 = E5 * E5;      \
        float E11 = E6 * E5, E12 = E6 * E6, E13 = E7 * E6;    \
        float E14 = E7 * E7, E15 = E8 * E7, E16 = E8 * E8;    \
        D0 = {E1, E2, E3, E4};                                \
        D1 = {E5, E6, E7, E8};                                \
        D2 = {E9, E10, E11, E12};                             \
        D3 = {E13, E14, E15, E16};                            \
    }

#define UPD4D(H, DA, BV)                          \
    H.x = DA.x * H.x + du * BV.x;                 \
    H.y = DA.y * H.y + du * BV.y;                 \
    H.z = DA.z * H.z + du * BV.z;                 \
    H.w = DA.w * H.w + du * BV.w;

#define UPD4E(H, A, BV)                                  \
    H.x = __expf(dt * A.x) * H.x + du * BV.x;            \
    H.y = __expf(dt * A.y) * H.y + du * BV.y;            \
    H.z = __expf(dt * A.z) * H.z + du * BV.z;            \
    H.w = __expf(dt * A.w) * H.w + du * BV.w;

// ---------------- scan pass 1: per-chunk local scan (h0 = 0) -------------------
__global__ __launch_bounds__(128, 4) void k_scan1(const float* __restrict__ u,
                                                  const float* __restrict__ xdbl,
                                                  const float* __restrict__ dpw,
                                                  const float* __restrict__ dpb,
                                                  const float* __restrict__ Alog,
                                                  float* __restrict__ cS,
                                                  float* __restrict__ cDT) {
    int blk = blockIdx.x;   // b*NC + c
    int b = blk / NC;
    int c = blk % NC;
    int d = threadIdx.x;
    float4 a0v, a1v, a2v, a3v;
    float a0;
    bool fast = load_a_struct(Alog, d, a0v, a1v, a2v, a3v, a0);
    float4 w = *reinterpret_cast<const float4*>(dpw + d * 4);
    float bb = dpb[d];
    float4 h0 = {0, 0, 0, 0}, h1 = {0, 0, 0, 0}, h2 = {0, 0, 0, 0}, h3 = {0, 0, 0, 0};
    float sdt = 0.f;
    int t0 = c * CS;
    if (fast) {
        for (int tt = 0; tt < CS; ++tt) {
            size_t base = (size_t)b * HW + t0 + tt;
            const float4* xd4 = reinterpret_cast<const float4*>(xdbl + base * 36);
            float4 x0 = xd4[0];
            float4 B0 = xd4[1], B1 = xd4[2], B2 = xd4[3], B3 = xd4[4];
            float dt = softplus_f(w.x * x0.x + w.y * x0.y + w.z * x0.z + w.w * x0.w + bb);
            float du = dt * u[base * DI + d];
            sdt += dt;
            float4 D0, D1, D2, D3;
            POWERS(dt, a0, D0, D1, D2, D3)
            UPD4D(h0, D0, B0) UPD4D(h1, D1, B1) UPD4D(h2, D2, B2) UPD4D(h3, D3, B3)
        }
    } else {
        for (int tt = 0; tt < CS; ++tt) {
            size_t base = (size_t)b * HW + t0 + tt;
            const float4* xd4 = reinterpret_cast<const float4*>(xdbl + base * 36);
            float4 x0 = xd4[0];
            float4 B0 = xd4[1], B1 = xd4[2], B2 = xd4[3], B3 = xd4[4];
            float dt = softplus_f(w.x * x0.x + w.y * x0.y + w.z * x0.z + w.w * x0.w + bb);
            float du = dt * u[base * DI + d];
            sdt += dt;
            UPD4E(h0, a0v, B0) UPD4E(h1, a1v, B1) UPD4E(h2, a2v, B2) UPD4E(h3, a3v, B3)
        }
    }
    size_t o = (size_t)blk * DI + d;
    cDT[o] = sdt;
    float4* cs4 = reinterpret_cast<float4*>(cS + o * NS);
    cs4[0] = h0; cs4[1] = h1; cs4[2] = h2; cs4[3] = h3;
}

// ------ scan pass 2: sequential chunk combine per (b,d,n), IN PLACE on cS ------
// After this kernel, cS[b,c,d,n] holds the INITIAL state for chunk c.
__global__ __launch_bounds__(256) void k_scan2(float* __restrict__ cS,
                                               const float* __restrict__ cDT,
                                               const float* __restrict__ Alog) {
    int idx = blockIdx.x * 256 + threadIdx.x;          // over Bn*DI*NS
    if (idx >= Bn * DI * NS) return;
    int n = idx & 15;
    int d = (idx >> 4) & 127;
    int b = idx >> 11;
    float a = -__expf(Alog[d * NS + n]);
    float h = 0.f;
    for (int c = 0; c < NC; ++c) {
        size_t o = (size_t)(b * NC + c) * DI + d;
        float s = cS[o * NS + n];
        cS[o * NS + n] = h;
        h = __expf(a * cDT[o]) * h + s;
    }
}

// ------- scan pass 3: re-scan with proper h0, emit gated y (overwrites u) ------
__global__ __launch_bounds__(128, 4) void k_scan3(float* __restrict__ uy,
                                                  const float* __restrict__ xz,
                                                  const float* __restrict__ xdbl,
                                                  const float* __restrict__ dpw,
                                                  const float* __restrict__ dpb,
                                                  const float* __restrict__ Alog,
                                                  const float* __restrict__ Dp,
                                                  const float* __restrict__ iS) {
    int blk = blockIdx.x;
    int b = blk / NC;
    int c = blk % NC;
    int d = threadIdx.x;
    float4 a0v, a1v, a2v, a3v;
    float a0;
    bool fast = load_a_struct(Alog, d, a0v, a1v, a2v, a3v, a0);
    float4 w = *reinterpret_cast<const float4*>(dpw + d * 4);
    float bb = dpb[d];
    float Dv = Dp[d];
    size_t so = (size_t)blk * DI + d;
    const float4* is4 = reinterpret_cast<const float4*>(iS + so * NS);
    float4 h0 = is4[0], h1 = is4[1], h2 = is4[2], h3 = is4[3];
    int t0 = c * CS;
    if (fast) {
        for (int tt = 0; tt < CS; ++tt) {
            size_t base = (size_t)b * HW + t0 + tt;
            const float4* xd4 = reinterpret_cast<const float4*>(xdbl + base * 36);
            float4 x0 = xd4[0];
            float4 B0 = xd4[1], B1 = xd4[2], B2 = xd4[3], B3 = xd4[4];
            float4 C0 = xd4[5], C1 = xd4[6], C2 = xd4[7], C3 = xd4[8];
            float dt = softplus_f(w.x * x0.x + w.y * x0.y + w.z * x0.z + w.w * x0.w + bb);
            float uu = uy[base * DI + d];
            float du = dt * uu;
            float4 D0, D1, D2, D3;
            POWERS(dt, a0, D0, D1, D2, D3)
            UPD4D(h0, D0, B0) UPD4D(h1, D1, B1) UPD4D(h2, D2, B2) UPD4D(h3, D3, B3)
            float y = h0.x * C0.x + h0.y * C0.y + h0.z * C0.z + h0.w * C0.w
                    + h1.x * C1.x + h1.y * C1.y + h1.z * C1.z + h1.w * C1.w
                    + h2.x * C2.x + h2.y * C2.y + h2.z * C2.z + h2.w * C2.w
                    + h3.x * C3.x + h3.y * C3.y + h3.z * C3.z + h3.w * C3.w;
            y += uu * Dv;
            float zz = xz[base * 256 + 128 + d];
            y *= zz * sigmoid_f(zz);
            uy[base * DI + d] = y;
        }
    } else {
        for (int tt = 0; tt < CS; ++tt) {
            size_t base = (size_t)b * HW + t0 + tt;
            const float4* xd4 = reinterpret_cast<const float4*>(xdbl + base * 36);
            float4 x0 = xd4[0];
            float4 B0 = xd4[1], B1 = xd4[2], B2 = xd4[3], B3 = xd4[4];
            float4 C0 = xd4[5], C1 = xd4[6], C2 = xd4[7], C3 = xd4[8];
            float dt = softplus_f(w.x * x0.x + w.y * x0.y + w.z * x0.z + w.w * x0.w + bb);
            float uu = uy[base * DI + d];
            float du = dt * uu;
            UPD4E(h0, a0v, B0) UPD4E(h1, a1v, B1) UPD4E(h2, a2v, B2) UPD4E(h3, a3v, B3)
            float y = h0.x * C0.x + h0.y * C0.y + h0.z * C0.z + h0.w * C0.w
                    + h1.x * C1.x + h1.y * C1.y + h1.z * C1.z + h1.w * C1.w
                    + h2.x * C2.x + h2.y * C2.y + h2.z * C2.z + h2.w * C2.w
                    + h3.x * C3.x + h3.y * C3.y + h3.z * C3.z + h3.w * C3.w;
            y += uu * Dv;
            float zz = xz[base * 256 + 128 + d];
            y *= zz * sigmoid_f(zz);
            uy[base * DI + d] = y;
        }
    }
}

// ---------------- layernorm over last dim (64), in place -----------------------
__global__ __launch_bounds__(256) void k_ln(float* __restrict__ feat,
                                            const float* __restrict__ g,
                                            const float* __restrict__ bta, int R) {
    int lane = threadIdx.x & 63;
    int wv = blockIdx.x * 4 + (threadIdx.x >> 6);
    int stride = gridDim.x * 4;
    for (int row = wv; row < R; row += stride) {
        float x = feat[(size_t)row * 64 + lane];
        float s = x;
#pragma unroll
        for (int off = 32; off; off >>= 1) s += __shfl_xor(s, off, 64);
        float mu = s * (1.f / 64.f);
        float xm = x - mu;
        float v = xm * xm;
#pragma unroll
        for (int off = 32; off; off >>= 1) v += __shfl_xor(v, off, 64);
        float var = v * (1.f / 64.f);
        feat[(size_t)row * 64 + lane] = xm * rsqrtf(var + 1e-5f) * g[lane] + bta[lane];
    }
}

// ---------------- head + residual: out = z - (feat @ head_w.T + head_b) --------
__global__ __launch_bounds__(256) void k_head(const float* __restrict__ feat,
                                              const float* __restrict__ hwt,
                                              const float* __restrict__ hb,
                                              const float* __restrict__ z,
                                              float* __restrict__ out) {
    __shared__ float fl[64 * 65];
    int row0 = blockIdx.x * 64;
    for (int i = threadIdx.x; i < 64 * 64; i += 256) {
        int r = i >> 6;
        int m = i & 63;
        fl[r * 65 + m] = feat[(size_t)(row0 + r) * 64 + m];
    }
    __syncthreads();
    int r = threadIdx.x >> 2;
    int c = threadIdx.x & 3;
    float acc = hb[c];
#pragma unroll
    for (int m = 0; m < 64; ++m) acc += fl[r * 65 + m] * hwt[c * 64 + m];
    int bl = row0 + r;
    int b = bl >> 12;
    int hw = bl & 4095;
    size_t o = ((size_t)b * 4 + c) * HW + hw;
    out[o] = z[o] - acc;
}

// -------------------------------------------------------------------------------
static void run_mamba(const float* const* P, float* feat, float* xz, float* u,
                      float* xdbl, float* cS, float* cDT, hipStream_t s) {
    // P: 0 in_proj_w, 1 conv_w, 2 conv_b, 3 x_proj_w, 4 dt_proj_w, 5 dt_proj_b,
    //    6 A_log, 7 D, 8 out_proj_w
    k_gemm<64, 64, 4><<<dim3(BL / 64, 4), 256, 0, s>>>(feat, P[0], xz, 256);
    k_conv<<<(BL * DI) / 256, 256, 0, s>>>(xz, P[1], P[2], u);
    k_gemm<128, 36, 3><<<dim3(BL / 64, 1), 256, 0, s>>>(u, P[3], xdbl, 36);
    k_scan1<<<Bn * NC, DI, 0, s>>>(u, xdbl, P[4], P[5], P[6], cS, cDT);
    k_scan2<<<(Bn * DI * NS) / 256, 256, 0, s>>>(cS, cDT, P[6]);
    k_scan3<<<Bn * NC, DI, 0, s>>>(u, xz, xdbl, P[4], P[5], P[6], P[7], cS);
    k_gemm<128, 64, 4><<<dim3(BL / 64, 1), 256, 0, s>>>(u, P[8], feat, 64);
}

extern "C" void kernel_launch(void* const* d_in, const int* in_sizes, int n_in,
                              void* d_out, int out_size, void* d_ws, size_t ws_size,
                              hipStream_t stream) {
    const float* z = (const float*)d_in[0];
    const float* ew = (const float*)d_in[1];
    const float* eb = (const float*)d_in[2];
    const float* m1[9];
    const float* m2[9];
    for (int i = 0; i < 9; ++i) m1[i] = (const float*)d_in[3 + i];
    for (int i = 0; i < 9; ++i) m2[i] = (const float*)d_in[12 + i];
    const float* ln1g = (const float*)d_in[21];
    const float* ln1b = (const float*)d_in[22];
    const float* ln2g = (const float*)d_in[23];
    const float* ln2b = (const float*)d_in[24];
    const float* hwt = (const float*)d_in[25];
    const float* hb = (const float*)d_in[26];

    float* ws = (float*)d_ws;
    float* feat = ws;                         // BL*64
    float* xz = feat + (size_t)BL * 64;       // BL*256
    float* u = xz + (size_t)BL * 256;         // BL*128
    float* xdbl = u + (size_t)BL * 128;       // BL*36
    float* cS = xdbl + (size_t)BL * 36;       // Bn*NC*DI*NS
    float* cDT = cS + (size_t)Bn * NC * DI * NS;  // Bn*NC*DI

    k_embed<<<(BL * DM) / 256, 256, 0, stream>>>(z, ew, eb, feat);

    run_mamba(m1, feat, xz, u, xdbl, cS, cDT, stream);
    k_ln<<<4096, 256, 0, stream>>>(feat, ln1g, ln1b, BL);
    run_mamba(m2, feat, xz, u, xdbl, cS, cDT, stream);
    k_ln<<<4096, 256, 0, stream>>>(feat, ln2g, ln2b, BL);

    k_head<<<BL / 64, 256, 0, stream>>>(feat, hwt, hb, z, (float*)d_out);
}

// Round 10
// 549.303 us; speedup vs baseline: 2.0025x; 1.0267x over previous
//
#include <hip/hip_runtime.h>
#include <hip/hip_bf16.h>

#define DEV __device__ __forceinline__

static constexpr int Bn = 16;
static constexpr int Cc = 4;
static constexpr int HW = 4096;      // L (=64*64)
static constexpr int BL = Bn * HW;   // 65536 rows
static constexpr int DM = 64;
static constexpr int DI = 128;
static constexpr int NS = 16;        // D_STATE
static constexpr int NC = 256;       // chunks per sequence
static constexpr int CS = HW / NC;   // 16 steps per chunk

DEV float sigmoid_f(float x) { return 1.f / (1.f + __expf(-x)); }
DEV float softplus_f(float x) {
    return fmaxf(x, 0.f) + __logf(1.f + __expf(-fabsf(x)));
}
DEV float silu_f(float x) { return x / (1.f + __expf(-x)); }

// ---------------- embed: feat[b,l,m] = sum_c z[b,c,l]*ew[m,c] + eb[m] ----------
__global__ __launch_bounds__(256) void k_embed(const float* __restrict__ z,
                                               const float* __restrict__ ew,
                                               const float* __restrict__ eb,
                                               float* __restrict__ feat) {
    int idx = blockIdx.x * 256 + threadIdx.x;          // over BL*DM
    if (idx >= BL * DM) return;
    int m = idx & 63;
    int bl = idx >> 6;
    int b = bl >> 12;
    int hw = bl & 4095;
    const float* zp = z + (size_t)b * Cc * HW + hw;
    float acc = eb[m];
#pragma unroll
    for (int c = 0; c < 4; ++c) acc += zp[(size_t)c * HW] * ew[m * 4 + c];
    feat[idx] = acc;
}

// ---- register-tiled GEMM: out[r, n0+c] = sum_k in[r,k] * W[n0+c, k] -----------
template <int K, int BN, int TN, int TM>
__global__ __launch_bounds__(256) void k_gemm(const float* __restrict__ in,
                                              const float* __restrict__ W,
                                              float* __restrict__ out,
                                              int Nfull) {
    constexpr int BM = 64;
    constexpr int CT = BN / TN;
    constexpr int RT = BM / TM;
    constexpr int KP = K + 4;
    constexpr int WP = BN + 4;
    __shared__ float As[BM * KP];
    __shared__ float Ws[K * WP];
    int tid = threadIdx.x;
    int n0 = blockIdx.y * BN;
    int row0 = blockIdx.x * BM;
    for (int i = tid; i < BN * (K / 4); i += 256) {
        int c = i / (K / 4);
        int k4 = i - c * (K / 4);
        float4 w = *reinterpret_cast<const float4*>(&W[(size_t)(n0 + c) * K + k4 * 4]);
        Ws[(k4 * 4 + 0) * WP + c] = w.x;
        Ws[(k4 * 4 + 1) * WP + c] = w.y;
        Ws[(k4 * 4 + 2) * WP + c] = w.z;
        Ws[(k4 * 4 + 3) * WP + c] = w.w;
    }
    for (int i = tid; i < BM * (K / 4); i += 256) {
        int r = i / (K / 4);
        int k4 = i - r * (K / 4);
        *reinterpret_cast<float4*>(&As[r * KP + k4 * 4]) =
            *reinterpret_cast<const float4*>(&in[(size_t)(row0 + r) * K + k4 * 4]);
    }
    __syncthreads();
    if (tid < CT * RT) {
        int ty = tid / CT, tx = tid - (tid / CT) * CT;
        int r0 = ty * TM, c0 = tx * TN;
        float acc[TM][TN];
#pragma unroll
        for (int i = 0; i < TM; ++i)
#pragma unroll
            for (int c = 0; c < TN; ++c) acc[i][c] = 0.f;
        for (int k = 0; k < K; k += 4) {
            float4 a[TM];
#pragma unroll
            for (int i = 0; i < TM; ++i)
                a[i] = *reinterpret_cast<const float4*>(&As[(r0 + i) * KP + k]);
            float bv[4][TN];
#pragma unroll
            for (int j = 0; j < 4; ++j)
#pragma unroll
                for (int c = 0; c < TN; ++c) bv[j][c] = Ws[(k + j) * WP + c0 + c];
#pragma unroll
            for (int i = 0; i < TM; ++i)
#pragma unroll
                for (int c = 0; c < TN; ++c)
                    acc[i][c] += a[i].x * bv[0][c] + a[i].y * bv[1][c]
                               + a[i].z * bv[2][c] + a[i].w * bv[3][c];
        }
#pragma unroll
        for (int i = 0; i < TM; ++i) {
            size_t o = (size_t)(row0 + r0 + i) * Nfull + n0 + c0;
            if constexpr (TN == 4) {
                float4 v = {acc[i][0], acc[i][1], acc[i][2], acc[i][3]};
                *reinterpret_cast<float4*>(&out[o]) = v;
            } else {
#pragma unroll
                for (int c = 0; c < TN; ++c) out[o + c] = acc[i][c];
            }
        }
    }
}

// ---- x_proj with fused causal conv+SiLU ---------------------------------------
// xdbl[r, c] = sum_d silu(conv(xz)[r,d]) * W[c,d];  W = x_proj_w [36][128]
__global__ __launch_bounds__(256) void k_xproj(const float* __restrict__ xz,
                                               const float* __restrict__ W,
                                               const float* __restrict__ cw,
                                               const float* __restrict__ cb,
                                               float* __restrict__ xdbl) {
    constexpr int BM = 64, K = 128, BN = 36, TN = 3, TM = 4;
    constexpr int CT = BN / TN;   // 12
    constexpr int RT = BM / TM;   // 16
    constexpr int KP = K + 4;     // 132
    constexpr int WP = BN + 4;    // 40
    __shared__ float Xs[(BM + 3) * KP];   // rows: x[row0-3 .. row0+63]; later rows 0..63 = u
    __shared__ float Ws[K * WP];
    int tid = threadIdx.x;
    int row0 = blockIdx.x * BM;
    bool first = (row0 & 4095) == 0;      // tile at batch start -> zero halo
    // stage W transposed
    for (int i = tid; i < BN * (K / 4); i += 256) {
        int c = i / (K / 4);
        int k4 = i - c * (K / 4);
        float4 w = *reinterpret_cast<const float4*>(&W[(size_t)c * K + k4 * 4]);
        Ws[(k4 * 4 + 0) * WP + c] = w.x;
        Ws[(k4 * 4 + 1) * WP + c] = w.y;
        Ws[(k4 * 4 + 2) * WP + c] = w.z;
        Ws[(k4 * 4 + 3) * WP + c] = w.w;
    }
    // stage raw x tile (u-half of xz), rows -3..63
    for (int i = tid; i < (BM + 3) * (K / 4); i += 256) {
        int r = i / (K / 4);              // 0..66; global row = row0 - 3 + r
        int k4 = i - r * (K / 4);
        float4 v = {0, 0, 0, 0};
        if (!first || r >= 3)
            v = *reinterpret_cast<const float4*>(&xz[(size_t)(row0 - 3 + r) * 256 + k4 * 4]);
        *reinterpret_cast<float4*>(&Xs[r * KP + k4 * 4]) = v;
    }
    __syncthreads();
    // compute u = silu(conv(x)) : thread owns 8 rows x 4 cols
    {
        int rg = tid >> 5;                 // 0..7 -> rows rg*8 .. rg*8+7 (output rows)
        int c0 = (tid & 31) * 4;
        float4 wr[4];                      // wr[j] = conv taps for col c0+j
#pragma unroll
        for (int j = 0; j < 4; ++j)
            wr[j] = *reinterpret_cast<const float4*>(&cw[(c0 + j) * 4]);
        float4 cb4 = *reinterpret_cast<const float4*>(&cb[c0]);
        int R0 = rg * 8;
        float4 xr[11];
#pragma unroll
        for (int j = 0; j < 11; ++j)
            xr[j] = *reinterpret_cast<const float4*>(&Xs[(R0 + j) * KP + c0]);
        float4 ur[8];
#pragma unroll
        for (int j = 0; j < 8; ++j) {
            float4 acc;
            acc.x = cb4.x + wr[0].x * xr[j].x + wr[0].y * xr[j + 1].x + wr[0].z * xr[j + 2].x + wr[0].w * xr[j + 3].x;
            acc.y = cb4.y + wr[1].x * xr[j].y + wr[1].y * xr[j + 1].y + wr[1].z * xr[j + 2].y + wr[1].w * xr[j + 3].y;
            acc.z = cb4.z + wr[2].x * xr[j].z + wr[2].y * xr[j + 1].z + wr[2].z * xr[j + 2].z + wr[2].w * xr[j + 3].z;
            acc.w = cb4.w + wr[3].x * xr[j].w + wr[3].y * xr[j + 1].w + wr[3].z * xr[j + 2].w + wr[3].w * xr[j + 3].w;
            ur[j].x = silu_f(acc.x);
            ur[j].y = silu_f(acc.y);
            ur[j].z = silu_f(acc.z);
            ur[j].w = silu_f(acc.w);
        }
        __syncthreads();
#pragma unroll
        for (int j = 0; j < 8; ++j)
            *reinterpret_cast<float4*>(&Xs[(R0 + j) * KP + c0]) = ur[j];
    }
    __syncthreads();
    if (tid < CT * RT) {
        int ty = tid / CT, tx = tid - (tid / CT) * CT;
        int r0 = ty * TM, c0 = tx * TN;
        float acc[TM][TN];
#pragma unroll
        for (int i = 0; i < TM; ++i)
#pragma unroll
            for (int c = 0; c < TN; ++c) acc[i][c] = 0.f;
        for (int k = 0; k < K; k += 4) {
            float4 a[TM];
#pragma unroll
            for (int i = 0; i < TM; ++i)
                a[i] = *reinterpret_cast<const float4*>(&Xs[(r0 + i) * KP + k]);
            float bv[4][TN];
#pragma unroll
            for (int j = 0; j < 4; ++j)
#pragma unroll
                for (int c = 0; c < TN; ++c) bv[j][c] = Ws[(k + j) * WP + c0 + c];
#pragma unroll
            for (int i = 0; i < TM; ++i)
#pragma unroll
                for (int c = 0; c < TN; ++c)
                    acc[i][c] += a[i].x * bv[0][c] + a[i].y * bv[1][c]
                               + a[i].z * bv[2][c] + a[i].w * bv[3][c];
        }
#pragma unroll
        for (int i = 0; i < TM; ++i) {
            size_t o = (size_t)(row0 + r0 + i) * BN + c0;
#pragma unroll
            for (int c = 0; c < TN; ++c) xdbl[o + c] = acc[i][c];
        }
    }
}

// ---- helpers for the scan kernels --------------------------------------------
DEV bool load_a_struct(const float* Alog, int d, float4& a0v, float4& a1v,
                       float4& a2v, float4& a3v, float& a0) {
    const float4* al = reinterpret_cast<const float4*>(Alog + d * NS);
    float4 t0 = al[0], t1 = al[1], t2 = al[2], t3 = al[3];
    a0v.x = -__expf(t0.x); a0v.y = -__expf(t0.y); a0v.z = -__expf(t0.z); a0v.w = -__expf(t0.w);
    a1v.x = -__expf(t1.x); a1v.y = -__expf(t1.y); a1v.z = -__expf(t1.z); a1v.w = -__expf(t1.w);
    a2v.x = -__expf(t2.x); a2v.y = -__expf(t2.y); a2v.z = -__expf(t2.z); a2v.w = -__expf(t2.w);
    a3v.x = -__expf(t3.x); a3v.y = -__expf(t3.y); a3v.z = -__expf(t3.z); a3v.w = -__expf(t3.w);
    a0 = a0v.x;
    float aa[16] = {a0v.x, a0v.y, a0v.z, a0v.w, a1v.x, a1v.y, a1v.z, a1v.w,
                    a2v.x, a2v.y, a2v.z, a2v.w, a3v.x, a3v.y, a3v.z, a3v.w};
    bool fast = true;
#pragma unroll
    for (int n = 0; n < 16; ++n)
        fast = fast && (fabsf(aa[n] - a0 * (float)(n + 1)) <= 1e-4f * (float)(n + 1));
    return fast;
}

#define POWERS(dt, a0, D0, D1, D2, D3)                        \
    {                                                         \
        float E1 = __expf((dt) * (a0));                       \
        float E2 = E1 * E1, E3 = E2 * E1, E4 = E2 * E2;       \
        float E5 = E3 * E2, E6 = E3 * E3, E7 = E4 * E3;       \
        float E8 = E4 * E4, E9 = E5 * E4, E10 = E5 * E5;      \
        float E11 = E6 * E5, E12 = E6 * E6, E13 = E7 * E6;    \
        float E14 = E7 * E7, E15 = E8 * E7, E16 = E8 * E8;    \
        D0 = {E1, E2, E3, E4};                                \
        D1 = {E5, E6, E7, E8};                                \
        D2 = {E9, E10, E11, E12};                             \
        D3 = {E13, E14, E15, E16};                            \
    }

#define UPD4D(H, DA, BV)                          \
    H.x = DA.x * H.x + du * BV.x;                 \
    H.y = DA.y * H.y + du * BV.y;                 \
    H.z = DA.z * H.z + du * BV.z;                 \
    H.w = DA.w * H.w + du * BV.w;

#define UPD4E(H, A, BV)                                  \
    H.x = __expf(dt * A.x) * H.x + du * BV.x;            \
    H.y = __expf(dt * A.y) * H.y + du * BV.y;            \
    H.z = __expf(dt * A.z) * H.z + du * BV.z;            \
    H.w = __expf(dt * A.w) * H.w + du * BV.w;

// conv warm-up: window = x[t0-3], x[t0-2], x[t0-1]
#define CONV_WARMUP                                                     \
    float x3 = 0.f, x2 = 0.f, x1 = 0.f;                                 \
    if (c != 0) {                                                       \
        size_t wb = ((size_t)b * HW + t0) * 256 + d;                    \
        x3 = xz[wb - 3 * 256];                                          \
        x2 = xz[wb - 2 * 256];                                          \
        x1 = xz[wb - 1 * 256];                                          \
    }

// per-step fused conv+SiLU; produces uu, advances window
#define CONV_STEP(base)                                                 \
    float xv = xz[(base) * 256 + d];                                    \
    float cacc = cbv + cwv.x * x3 + cwv.y * x2 + cwv.z * x1 + cwv.w * xv; \
    float uu = cacc * sigmoid_f(cacc);                                  \
    x3 = x2; x2 = x1; x1 = xv;

// ---------------- scan pass 1: per-chunk local scan (h0 = 0) -------------------
__global__ __launch_bounds__(128, 4) void k_scan1(const float* __restrict__ xz,
                                                  const float* __restrict__ xdbl,
                                                  const float* __restrict__ dpw,
                                                  const float* __restrict__ dpb,
                                                  const float* __restrict__ Alog,
                                                  const float* __restrict__ cw,
                                                  const float* __restrict__ cb,
                                                  float* __restrict__ cS,
                                                  float* __restrict__ cDT) {
    int blk = blockIdx.x;   // b*NC + c
    int b = blk / NC;
    int c = blk % NC;
    int d = threadIdx.x;
    float4 a0v, a1v, a2v, a3v;
    float a0;
    bool fast = load_a_struct(Alog, d, a0v, a1v, a2v, a3v, a0);
    float4 w = *reinterpret_cast<const float4*>(dpw + d * 4);
    float bb = dpb[d];
    float4 cwv = *reinterpret_cast<const float4*>(cw + d * 4);
    float cbv = cb[d];
    float4 h0 = {0, 0, 0, 0}, h1 = {0, 0, 0, 0}, h2 = {0, 0, 0, 0}, h3 = {0, 0, 0, 0};
    float sdt = 0.f;
    int t0 = c * CS;
    CONV_WARMUP
    if (fast) {
        for (int tt = 0; tt < CS; ++tt) {
            size_t base = (size_t)b * HW + t0 + tt;
            const float4* xd4 = reinterpret_cast<const float4*>(xdbl + base * 36);
            float4 x0 = xd4[0];
            float4 B0 = xd4[1], B1 = xd4[2], B2 = xd4[3], B3 = xd4[4];
            float dt = softplus_f(w.x * x0.x + w.y * x0.y + w.z * x0.z + w.w * x0.w + bb);
            CONV_STEP(base)
            float du = dt * uu;
            sdt += dt;
            float4 D0, D1, D2, D3;
            POWERS(dt, a0, D0, D1, D2, D3)
            UPD4D(h0, D0, B0) UPD4D(h1, D1, B1) UPD4D(h2, D2, B2) UPD4D(h3, D3, B3)
        }
    } else {
        for (int tt = 0; tt < CS; ++tt) {
            size_t base = (size_t)b * HW + t0 + tt;
            const float4* xd4 = reinterpret_cast<const float4*>(xdbl + base * 36);
            float4 x0 = xd4[0];
            float4 B0 = xd4[1], B1 = xd4[2], B2 = xd4[3], B3 = xd4[4];
            float dt = softplus_f(w.x * x0.x + w.y * x0.y + w.z * x0.z + w.w * x0.w + bb);
            CONV_STEP(base)
            float du = dt * uu;
            sdt += dt;
            UPD4E(h0, a0v, B0) UPD4E(h1, a1v, B1) UPD4E(h2, a2v, B2) UPD4E(h3, a3v, B3)
        }
    }
    size_t o = (size_t)blk * DI + d;
    cDT[o] = sdt;
    float4* cs4 = reinterpret_cast<float4*>(cS + o * NS);
    cs4[0] = h0; cs4[1] = h1; cs4[2] = h2; cs4[3] = h3;
}

// ------ scan pass 2: sequential chunk combine per (b,d,n), IN PLACE on cS ------
__global__ __launch_bounds__(256) void k_scan2(float* __restrict__ cS,
                                               const float* __restrict__ cDT,
                                               const float* __restrict__ Alog) {
    int idx = blockIdx.x * 256 + threadIdx.x;          // over Bn*DI*NS
    if (idx >= Bn * DI * NS) return;
    int n = idx & 15;
    int d = (idx >> 4) & 127;
    int b = idx >> 11;
    float a = -__expf(Alog[d * NS + n]);
    float h = 0.f;
    for (int c = 0; c < NC; ++c) {
        size_t o = (size_t)(b * NC + c) * DI + d;
        float s = cS[o * NS + n];
        cS[o * NS + n] = h;
        h = __expf(a * cDT[o]) * h + s;
    }
}

// ------- scan pass 3: re-scan with proper h0, emit gated y into uy -------------
__global__ __launch_bounds__(128, 4) void k_scan3(float* __restrict__ uy,
                                                  const float* __restrict__ xz,
                                                  const float* __restrict__ xdbl,
                                                  const float* __restrict__ dpw,
                                                  const float* __restrict__ dpb,
                                                  const float* __restrict__ Alog,
                                                  const float* __restrict__ Dp,
                                                  const float* __restrict__ cw,
                                                  const float* __restrict__ cb,
                                                  const float* __restrict__ iS) {
    int blk = blockIdx.x;
    int b = blk / NC;
    int c = blk % NC;
    int d = threadIdx.x;
    float4 a0v, a1v, a2v, a3v;
    float a0;
    bool fast = load_a_struct(Alog, d, a0v, a1v, a2v, a3v, a0);
    float4 w = *reinterpret_cast<const float4*>(dpw + d * 4);
    float bb = dpb[d];
    float Dv = Dp[d];
    float4 cwv = *reinterpret_cast<const float4*>(cw + d * 4);
    float cbv = cb[d];
    size_t so = (size_t)blk * DI + d;
    const float4* is4 = reinterpret_cast<const float4*>(iS + so * NS);
    float4 h0 = is4[0], h1 = is4[1], h2 = is4[2], h3 = is4[3];
    int t0 = c * CS;
    CONV_WARMUP
    if (fast) {
        for (int tt = 0; tt < CS; ++tt) {
            size_t base = (size_t)b * HW + t0 + tt;
            const float4* xd4 = reinterpret_cast<const float4*>(xdbl + base * 36);
            float4 x0 = xd4[0];
            float4 B0 = xd4[1], B1 = xd4[2], B2 = xd4[3], B3 = xd4[4];
            float4 C0 = xd4[5], C1 = xd4[6], C2 = xd4[7], C3 = xd4[8];
            float dt = softplus_f(w.x * x0.x + w.y * x0.y + w.z * x0.z + w.w * x0.w + bb);
            CONV_STEP(base)
            float du = dt * uu;
            float4 D0, D1, D2, D3;
            POWERS(dt, a0, D0, D1, D2, D3)
            UPD4D(h0, D0, B0) UPD4D(h1, D1, B1) UPD4D(h2, D2, B2) UPD4D(h3, D3, B3)
            float y = h0.x * C0.x + h0.y * C0.y + h0.z * C0.z + h0.w * C0.w
                    + h1.x * C1.x + h1.y * C1.y + h1.z * C1.z + h1.w * C1.w
                    + h2.x * C2.x + h2.y * C2.y + h2.z * C2.z + h2.w * C2.w
                    + h3.x * C3.x + h3.y * C3.y + h3.z * C3.z + h3.w * C3.w;
            y += uu * Dv;
            float zz = xz[base * 256 + 128 + d];
            y *= zz * sigmoid_f(zz);
            uy[base * DI + d] = y;
        }
    } else {
        for (int tt = 0; tt < CS; ++tt) {
            size_t base = (size_t)b * HW + t0 + tt;
            const float4* xd4 = reinterpret_cast<const float4*>(xdbl + base * 36);
            float4 x0 = xd4[0];
            float4 B0 = xd4[1], B1 = xd4[2], B2 = xd4[3], B3 = xd4[4];
            float4 C0 = xd4[5], C1 = xd4[6], C2 = xd4[7], C3 = xd4[8];
            float dt = softplus_f(w.x * x0.x + w.y * x0.y + w.z * x0.z + w.w * x0.w + bb);
            CONV_STEP(base)
            float du = dt * uu;
            UPD4E(h0, a0v, B0) UPD4E(h1, a1v, B1) UPD4E(h2, a2v, B2) UPD4E(h3, a3v, B3)
            float y = h0.x * C0.x + h0.y * C0.y + h0.z * C0.z + h0.w * C0.w
                    + h1.x * C1.x + h1.y * C1.y + h1.z * C1.z + h1.w * C1.w
                    + h2.x * C2.x + h2.y * C2.y + h2.z * C2.z + h2.w * C2.w
                    + h3.x * C3.x + h3.y * C3.y + h3.z * C3.z + h3.w * C3.w;
            y += uu * Dv;
            float zz = xz[base * 256 + 128 + d];
            y *= zz * sigmoid_f(zz);
            uy[base * DI + d] = y;
        }
    }
}

// ---------------- layernorm over last dim (64), in place -----------------------
__global__ __launch_bounds__(256) void k_ln(float* __restrict__ feat,
                                            const float* __restrict__ g,
                                            const float* __restrict__ bta, int R) {
    int lane = threadIdx.x & 63;
    int wv = blockIdx.x * 4 + (threadIdx.x >> 6);
    int stride = gridDim.x * 4;
    for (int row = wv; row < R; row += stride) {
        float x = feat[(size_t)row * 64 + lane];
        float s = x;
#pragma unroll
        for (int off = 32; off; off >>= 1) s += __shfl_xor(s, off, 64);
        float mu = s * (1.f / 64.f);
        float xm = x - mu;
        float v = xm * xm;
#pragma unroll
        for (int off = 32; off; off >>= 1) v += __shfl_xor(v, off, 64);
        float var = v * (1.f / 64.f);
        feat[(size_t)row * 64 + lane] = xm * rsqrtf(var + 1e-5f) * g[lane] + bta[lane];
    }
}

// ---------------- head + residual: out = z - (feat @ head_w.T + head_b) --------
__global__ __launch_bounds__(256) void k_head(const float* __restrict__ feat,
                                              const float* __restrict__ hwt,
                                              const float* __restrict__ hb,
                                              const float* __restrict__ z,
                                              float* __restrict__ out) {
    __shared__ float fl[64 * 65];
    int row0 = blockIdx.x * 64;
    for (int i = threadIdx.x; i < 64 * 64; i += 256) {
        int r = i >> 6;
        int m = i & 63;
        fl[r * 65 + m] = feat[(size_t)(row0 + r) * 64 + m];
    }
    __syncthreads();
    int r = threadIdx.x >> 2;
    int c = threadIdx.x & 3;
    float acc = hb[c];
#pragma unroll
    for (int m = 0; m < 64; ++m) acc += fl[r * 65 + m] * hwt[c * 64 + m];
    int bl = row0 + r;
    int b = bl >> 12;
    int hw = bl & 4095;
    size_t o = ((size_t)b * 4 + c) * HW + hw;
    out[o] = z[o] - acc;
}

// -------------------------------------------------------------------------------
static void run_mamba(const float* const* P, float* feat, float* xz, float* u,
                      float* xdbl, float* cS, float* cDT, hipStream_t s) {
    // P: 0 in_proj_w, 1 conv_w, 2 conv_b, 3 x_proj_w, 4 dt_proj_w, 5 dt_proj_b,
    //    6 A_log, 7 D, 8 out_proj_w
    k_gemm<64, 64, 4, 8><<<dim3(BL / 64, 4), 256, 0, s>>>(feat, P[0], xz, 256);
    k_xproj<<<BL / 64, 256, 0, s>>>(xz, P[3], P[1], P[2], xdbl);
    k_scan1<<<Bn * NC, DI, 0, s>>>(xz, xdbl, P[4], P[5], P[6], P[1], P[2], cS, cDT);
    k_scan2<<<(Bn * DI * NS) / 256, 256, 0, s>>>(cS, cDT, P[6]);
    k_scan3<<<Bn * NC, DI, 0, s>>>(u, xz, xdbl, P[4], P[5], P[6], P[7], P[1], P[2], cS);
    k_gemm<128, 64, 4, 8><<<dim3(BL / 64, 1), 256, 0, s>>>(u, P[8], feat, 64);
}

extern "C" void kernel_launch(void* const* d_in, const int* in_sizes, int n_in,
                              void* d_out, int out_size, void* d_ws, size_t ws_size,
                              hipStream_t stream) {
    const float* z = (const float*)d_in[0];
    const float* ew = (const float*)d_in[1];
    const float* eb = (const float*)d_in[2];
    const float* m1[9];
    const float* m2[9];
    for (int i = 0; i < 9; ++i) m1[i] = (const float*)d_in[3 + i];
    for (int i = 0; i < 9; ++i) m2[i] = (const float*)d_in[12 + i];
    const float* ln1g = (const float*)d_in[21];
    const float* ln1b = (const float*)d_in[22];
    const float* ln2g = (const float*)d_in[23];
    const float* ln2b = (const float*)d_in[24];
    const float* hwt = (const float*)d_in[25];
    const float* hb = (const float*)d_in[26];

    float* ws = (float*)d_ws;
    float* feat = ws;                         // BL*64
    float* xz = feat + (size_t)BL * 64;       // BL*256
    float* u = xz + (size_t)BL * 256;         // BL*128  (y output of scan3)
    float* xdbl = u + (size_t)BL * 128;       // BL*36
    float* cS = xdbl + (size_t)BL * 36;       // Bn*NC*DI*NS
    float* cDT = cS + (size_t)Bn * NC * DI * NS;  // Bn*NC*DI

    k_embed<<<(BL * DM) / 256, 256, 0, stream>>>(z, ew, eb, feat);

    run_mamba(m1, feat, xz, u, xdbl, cS, cDT, stream);
    k_ln<<<4096, 256, 0, stream>>>(feat, ln1g, ln1b, BL);
    run_mamba(m2, feat, xz, u, xdbl, cS, cDT, stream);
    k_ln<<<4096, 256, 0, stream>>>(feat, ln2g, ln2b, BL);

    k_head<<<BL / 64, 256, 0, stream>>>(feat, hwt, hb, z, (float*)d_out);
}